// Round 1
// baseline (740.627 us; speedup 1.0000x reference)
//
#include <hip/hip_runtime.h>
#include <cmath>
#include <cstdint>

// ---------------------------------------------------------------------------
// SeparateHiddenGCAEEncoder: 4 chained GCN convs, P = D^-1/2 (A+I) D^-1/2.
// Round 9: gather path attack.
//  - predicated 4-wide edge loop (no serial trailer; clamped idx + zeroed norm)
//  - csr quad lookahead with non-temporal loads (software pipeline the
//    csr -> gather dependent chain)
//  - fused conv1/conv2 gather: XL = [feature@W1 (128) | cond (64)] per node,
//    one CSR sweep emits tanh-part and cond-propagation part (384B/edge
//    contiguous reads, one csr sweep instead of two)
// ---------------------------------------------------------------------------

typedef _Float16 f16;
typedef _Float16 f16x8 __attribute__((ext_vector_type(8)));
typedef _Float16 f16x4 __attribute__((ext_vector_type(4)));
typedef float f32x4 __attribute__((ext_vector_type(4)));
typedef unsigned int u32x4 __attribute__((ext_vector_type(4)));
typedef unsigned int u32x2 __attribute__((ext_vector_type(2)));

// ---------------- CSR build ----------------
__global__ void count_zero_kernel(int* __restrict__ count, int N) {
    int i = blockIdx.x * 256 + threadIdx.x;
    if (i < N) count[i] = 0;
}

__global__ void count_rank_kernel(const int* __restrict__ dst, int* __restrict__ count,
                                  int* __restrict__ rank, int E) {
    int e = blockIdx.x * 256 + threadIdx.x;
    if (e < E) rank[e] = atomicAdd(&count[dst[e]], 1);
}

__global__ void dinv_kernel(const int* __restrict__ count, float* __restrict__ dinv, int N) {
    int i = blockIdx.x * 256 + threadIdx.x;
    if (i < N) dinv[i] = rsqrtf((float)(count[i] + 1));  // +1 self loop
}

constexpr int SCAN_VPT = 8;
constexpr int SCAN_TILE = 256 * SCAN_VPT;  // 2048

__global__ __launch_bounds__(256) void scan_partial_kernel(const int* __restrict__ count,
                                                           int* __restrict__ blocksums, int N) {
    __shared__ int red[256];
    const int t = threadIdx.x;
    int base = blockIdx.x * SCAN_TILE + t * SCAN_VPT;
    int s = 0;
#pragma unroll
    for (int i = 0; i < SCAN_VPT; ++i) {
        int idx = base + i;
        if (idx < N) s += count[idx];
    }
    red[t] = s;
    __syncthreads();
    for (int off = 128; off > 0; off >>= 1) {
        if (t < off) red[t] += red[t + off];
        __syncthreads();
    }
    if (t == 0) blocksums[blockIdx.x] = red[0];
}

__global__ __launch_bounds__(1024) void scan_blocksums_kernel(int* __restrict__ blocksums, int nb) {
    __shared__ int sh[1024];
    const int t = threadIdx.x;
    int v = (t < nb) ? blocksums[t] : 0;
    sh[t] = v;
    __syncthreads();
    for (int off = 1; off < 1024; off <<= 1) {
        int u = (t >= off) ? sh[t - off] : 0;
        __syncthreads();
        sh[t] += u;
        __syncthreads();
    }
    if (t < nb) blocksums[t] = sh[t] - v;  // exclusive
}

__global__ __launch_bounds__(256) void scan_final_kernel(const int* __restrict__ count,
                                                         const int* __restrict__ blocksums,
                                                         int* __restrict__ row_ptr, int N) {
    __shared__ int red[256];
    const int t = threadIdx.x;
    int base = blockIdx.x * SCAN_TILE + t * SCAN_VPT;
    int vals[SCAN_VPT];
    int s = 0;
#pragma unroll
    for (int i = 0; i < SCAN_VPT; ++i) {
        int idx = base + i;
        vals[i] = (idx < N) ? count[idx] : 0;
        s += vals[i];
    }
    red[t] = s;
    __syncthreads();
    for (int off = 1; off < 256; off <<= 1) {
        int u = (t >= off) ? red[t - off] : 0;
        __syncthreads();
        red[t] += u;
        __syncthreads();
    }
    int run = red[t] - s + blocksums[blockIdx.x];
#pragma unroll
    for (int i = 0; i < SCAN_VPT; ++i) {
        int idx = base + i;
        if (idx < N) {
            row_ptr[idx] = run;
            run += vals[i];
            if (idx == N - 1) row_ptr[N] = run;
        }
    }
}

__global__ void fill_kernel(const int* __restrict__ src, const int* __restrict__ dst,
                            const int* __restrict__ rank, const float* __restrict__ dinv,
                            const int* __restrict__ row_ptr, long long* __restrict__ csr, int E) {
    int e = blockIdx.x * 256 + threadIdx.x;
    if (e >= E) return;
    int s = src[e];
    int d = dst[e];
    int pos = row_ptr[d] + rank[e];
    float nrm = dinv[s] * dinv[d];
    long long v = ((long long)(unsigned)__float_as_int(nrm) << 32) | (unsigned)s;
    __builtin_nontemporal_store(v, csr + pos);
}

// ---------------- weight prep: W[K][M] fp32 -> Wt_hi/Wt_lo [M][K] f16 -------
__global__ void wprep_kernel(const float* __restrict__ W, f16* __restrict__ wt_hi,
                             f16* __restrict__ wt_lo, int K, int M) {
    int idx = blockIdx.x * 256 + threadIdx.x;
    if (idx >= K * M) return;
    int k = idx / M, m = idx % M;
    float w = W[idx];
    f16 h = (f16)w;
    wt_hi[(size_t)m * K + k] = h;
    wt_lo[(size_t)m * K + k] = (f16)(w - (float)h);
}

// ---------------- cond fp32 -> f16 into XL strip [node*192 + 128 .. +192) ---
__global__ void cond_to_xl_kernel(const float* __restrict__ x, f16* __restrict__ XL, int N) {
    int i = blockIdx.x * 256 + threadIdx.x;  // quad index, N*16 quads
    if (i >= N * 16) return;
    int node = i >> 4, q = i & 15;
    float4 v = ((const float4*)x)[i];
    union { f16 h[4]; uint2 u; } p;
    p.h[0] = (f16)v.x; p.h[1] = (f16)v.y; p.h[2] = (f16)v.z; p.h[3] = (f16)v.w;
    *(uint2*)(XL + (size_t)node * 192 + 128 + q * 4) = p.u;
}

// ---------------- f16 MFMA GEMM: out[N,M] = X[N,K] @ (Wh+Wl) (+bias,tanh) ---
// ldx = row stride of X (elements) so strips of wider arrays can be consumed.
template <int K, int M, bool BIAS_TANH, bool X_IS_HALF>
__global__ __launch_bounds__(256) void gemm_mfma_kernel(
    const void* __restrict__ Xv, const f16* __restrict__ Wth,
    const f16* __restrict__ Wtl, const float* __restrict__ bias,
    f16* __restrict__ out, int ld, int colOff, int ldx, int N) {
    constexpr int BM = 128, BK = 32, XP = 40;
    constexpr int SW = M / 4;    // column strip per wave (32 or 16)
    constexpr int CT = SW / 16;  // 16-col tiles per wave (2 or 1)
    constexpr int RT = BM / 16;  // 8 row tiles
    __shared__ f16 xs[BM * XP];
    __shared__ f16 whs[M * XP];
    __shared__ f16 wls[M * XP];

    const int tid = threadIdx.x;
    const int lane = tid & 63;
    const int wv = tid >> 6;
    const int m16 = lane & 15;
    const int quad = lane >> 4;
    const int row0 = blockIdx.x * BM;

    f32x4 acc[RT][CT];
#pragma unroll
    for (int rt = 0; rt < RT; ++rt)
#pragma unroll
        for (int ct = 0; ct < CT; ++ct) acc[rt][ct] = (f32x4){0.f, 0.f, 0.f, 0.f};

    for (int k0 = 0; k0 < K; k0 += BK) {
        if (X_IS_HALF) {
            const f16* X = (const f16*)Xv;
#pragma unroll
            for (int i = 0; i < 2; ++i) {
                int c = i * 256 + tid;
                int r = c >> 2, ko = (c & 3) * 8;
                uint4 v = make_uint4(0u, 0u, 0u, 0u);
                if (row0 + r < N) v = *(const uint4*)(X + (size_t)(row0 + r) * ldx + k0 + ko);
                *(uint4*)(&xs[r * XP + ko]) = v;
            }
        } else {
            const float* X = (const float*)Xv;
#pragma unroll
            for (int i = 0; i < 4; ++i) {
                int c = i * 256 + tid;
                int r = c >> 3, kq = (c & 7) * 4;
                float4 v = make_float4(0.f, 0.f, 0.f, 0.f);
                if (row0 + r < N) v = *(const float4*)(X + (size_t)(row0 + r) * ldx + k0 + kq);
                union { f16 h[4]; uint2 u; } p;
                p.h[0] = (f16)v.x; p.h[1] = (f16)v.y; p.h[2] = (f16)v.z; p.h[3] = (f16)v.w;
                *(uint2*)(&xs[r * XP + kq]) = p.u;
            }
        }
#pragma unroll
        for (int i = 0; i < (M * 4) / 256; ++i) {
            int c = i * 256 + tid;
            int n = c >> 2, ko = (c & 3) * 8;
            *(uint4*)(&whs[n * XP + ko]) = *(const uint4*)(Wth + (size_t)n * K + k0 + ko);
            *(uint4*)(&wls[n * XP + ko]) = *(const uint4*)(Wtl + (size_t)n * K + k0 + ko);
        }
        __syncthreads();

        f16x8 bh[CT], bl[CT];
#pragma unroll
        for (int ct = 0; ct < CT; ++ct) {
            bh[ct] = *(const f16x8*)(&whs[(wv * SW + ct * 16 + m16) * XP + quad * 8]);
            bl[ct] = *(const f16x8*)(&wls[(wv * SW + ct * 16 + m16) * XP + quad * 8]);
        }
#pragma unroll
        for (int rt = 0; rt < RT; ++rt) {
            f16x8 a = *(const f16x8*)(&xs[(rt * 16 + m16) * XP + quad * 8]);
#pragma unroll
            for (int ct = 0; ct < CT; ++ct) {
                acc[rt][ct] = __builtin_amdgcn_mfma_f32_16x16x32_f16(a, bh[ct], acc[rt][ct], 0, 0, 0);
                acc[rt][ct] = __builtin_amdgcn_mfma_f32_16x16x32_f16(a, bl[ct], acc[rt][ct], 0, 0, 0);
            }
        }
        __syncthreads();
    }

    float brs[CT];
    if (BIAS_TANH) {
#pragma unroll
        for (int ct = 0; ct < CT; ++ct) brs[ct] = bias[wv * SW + ct * 16 + m16];
    }

    // C/D layout: col = lane&15, row(within 16) = quad*4 + reg
#pragma unroll
    for (int rt = 0; rt < RT; ++rt) {
#pragma unroll
        for (int r = 0; r < 4; ++r) {
            int row = row0 + rt * 16 + quad * 4 + r;
            if (row < N) {
                f16* op = out + (size_t)row * ld + colOff + wv * SW + m16;
#pragma unroll
                for (int ct = 0; ct < CT; ++ct) {
                    float v = acc[rt][ct][r];
                    if (BIAS_TANH) v = tanhf(v + brs[ct]);
                    op[ct * 16] = (f16)v;
                }
            }
        }
    }
}

// ---------------- generic f16 gather, predicated loop + csr lookahead -------
template <int M, bool TANH, bool HAS_BIAS, bool OUT_F32>
__global__ __launch_bounds__(256) void gather_h_kernel(
    const f16* __restrict__ xl, const float* __restrict__ b,
    const float* __restrict__ dinv, const int* __restrict__ row_ptr,
    const long long* __restrict__ csr, void* __restrict__ outv,
    int ld, int colOff, int N) {
    constexpr int TPN = M / 8;  // threads per node (8 f16 = 16B each)
    int gid = blockIdx.x * 256 + threadIdx.x;
    int node = gid / TPN;
    int t = gid % TPN;
    if (node >= N) return;

    float di = dinv[node];
    float self = di * di;
    f16x8 x = *(const f16x8*)(xl + (size_t)node * M + t * 8);
    float acc[8];
#pragma unroll
    for (int j = 0; j < 8; ++j) acc[j] = (float)x[j] * self;
    if (HAS_BIAS) {
        float4 b0 = *(const float4*)(b + t * 8);
        float4 b1 = *(const float4*)(b + t * 8 + 4);
        acc[0] += b0.x; acc[1] += b0.y; acc[2] += b0.z; acc[3] += b0.w;
        acc[4] += b1.x; acc[5] += b1.y; acc[6] += b1.z; acc[7] += b1.w;
    }

    int p = row_ptr[node];
    const int p1 = row_ptr[node + 1];
    const int last = p1 - 1;
    long long e0 = 0, e1 = 0, e2 = 0, e3 = 0;
    if (p < p1) {
        e0 = __builtin_nontemporal_load(csr + p);
        e1 = __builtin_nontemporal_load(csr + (p + 1 < p1 ? p + 1 : last));
        e2 = __builtin_nontemporal_load(csr + (p + 2 < p1 ? p + 2 : last));
        e3 = __builtin_nontemporal_load(csr + (p + 3 < p1 ? p + 3 : last));
    }
    while (p < p1) {
        const long long c0 = e0, c1 = e1, c2 = e2, c3 = e3;
        const int pn = p + 4;
        if (pn < p1) {  // lookahead next quad (clamped; dup lines are L1/L2 hits)
            e0 = __builtin_nontemporal_load(csr + pn);
            e1 = __builtin_nontemporal_load(csr + (pn + 1 < p1 ? pn + 1 : last));
            e2 = __builtin_nontemporal_load(csr + (pn + 2 < p1 ? pn + 2 : last));
            e3 = __builtin_nontemporal_load(csr + (pn + 3 < p1 ? pn + 3 : last));
        }
        int s0 = (int)c0, s1 = (int)c1, s2 = (int)c2, s3 = (int)c3;
        float n0 = __int_as_float((int)(c0 >> 32));
        float n1 = (p + 1 < p1) ? __int_as_float((int)(c1 >> 32)) : 0.f;
        float n2 = (p + 2 < p1) ? __int_as_float((int)(c2 >> 32)) : 0.f;
        float n3 = (p + 3 < p1) ? __int_as_float((int)(c3 >> 32)) : 0.f;
        f16x8 v0 = *(const f16x8*)(xl + (size_t)s0 * M + t * 8);
        f16x8 v1 = *(const f16x8*)(xl + (size_t)s1 * M + t * 8);
        f16x8 v2 = *(const f16x8*)(xl + (size_t)s2 * M + t * 8);
        f16x8 v3 = *(const f16x8*)(xl + (size_t)s3 * M + t * 8);
#pragma unroll
        for (int j = 0; j < 8; ++j)
            acc[j] += ((float)v0[j] * n0 + (float)v1[j] * n1) +
                      ((float)v2[j] * n2 + (float)v3[j] * n3);
        p = pn;
    }

    if (TANH) {
#pragma unroll
        for (int j = 0; j < 8; ++j) acc[j] = tanhf(acc[j]);
    }

    if (OUT_F32) {
        float* op = (float*)outv + (size_t)node * ld + colOff + t * 8;
        f32x4 o0 = {acc[0], acc[1], acc[2], acc[3]};
        f32x4 o1 = {acc[4], acc[5], acc[6], acc[7]};
        __builtin_nontemporal_store(o0, (f32x4*)op);
        __builtin_nontemporal_store(o1, (f32x4*)(op + 4));
    } else {
        union { f16 h[8]; u32x4 u; } o;
#pragma unroll
        for (int j = 0; j < 8; ++j) o.h[j] = (f16)acc[j];
        __builtin_nontemporal_store(o.u, (u32x4*)((f16*)outv + (size_t)node * ld + colOff + t * 8));
    }
}

// ---------------- fused conv1/conv2 gather -------------------------------
// XL row layout: [xlA (128 f16) | cond (64 f16)] -> stride 192.
// One CSR sweep: outA = tanh(P*xlA + bA) -> out[:,0:128]  (f16, ld 256)
//                outC = P*cond           -> out[:,128:192] (f16, ld 256)
__global__ __launch_bounds__(256) void gather_fused_kernel(
    const f16* __restrict__ XL, const float* __restrict__ bA,
    const float* __restrict__ dinv, const int* __restrict__ row_ptr,
    const long long* __restrict__ csr, f16* __restrict__ out, int N) {
    int gid = blockIdx.x * 256 + threadIdx.x;
    int node = gid >> 4;
    int t = gid & 15;
    if (node >= N) return;

    float di = dinv[node];
    float self = di * di;
    const f16* base = XL + (size_t)node * 192;
    f16x8 xa = *(const f16x8*)(base + t * 8);
    f16x4 xc = *(const f16x4*)(base + 128 + t * 4);
    float accA[8], accC[4];
#pragma unroll
    for (int j = 0; j < 8; ++j) accA[j] = (float)xa[j] * self;
#pragma unroll
    for (int j = 0; j < 4; ++j) accC[j] = (float)xc[j] * self;
    {
        float4 b0 = *(const float4*)(bA + t * 8);
        float4 b1 = *(const float4*)(bA + t * 8 + 4);
        accA[0] += b0.x; accA[1] += b0.y; accA[2] += b0.z; accA[3] += b0.w;
        accA[4] += b1.x; accA[5] += b1.y; accA[6] += b1.z; accA[7] += b1.w;
    }

    int p = row_ptr[node];
    const int p1 = row_ptr[node + 1];
    const int last = p1 - 1;
    long long e0 = 0, e1 = 0, e2 = 0, e3 = 0;
    if (p < p1) {
        e0 = __builtin_nontemporal_load(csr + p);
        e1 = __builtin_nontemporal_load(csr + (p + 1 < p1 ? p + 1 : last));
        e2 = __builtin_nontemporal_load(csr + (p + 2 < p1 ? p + 2 : last));
        e3 = __builtin_nontemporal_load(csr + (p + 3 < p1 ? p + 3 : last));
    }
    while (p < p1) {
        const long long c0 = e0, c1 = e1, c2 = e2, c3 = e3;
        const int pn = p + 4;
        if (pn < p1) {
            e0 = __builtin_nontemporal_load(csr + pn);
            e1 = __builtin_nontemporal_load(csr + (pn + 1 < p1 ? pn + 1 : last));
            e2 = __builtin_nontemporal_load(csr + (pn + 2 < p1 ? pn + 2 : last));
            e3 = __builtin_nontemporal_load(csr + (pn + 3 < p1 ? pn + 3 : last));
        }
        int s0 = (int)c0, s1 = (int)c1, s2 = (int)c2, s3 = (int)c3;
        float n0 = __int_as_float((int)(c0 >> 32));
        float n1 = (p + 1 < p1) ? __int_as_float((int)(c1 >> 32)) : 0.f;
        float n2 = (p + 2 < p1) ? __int_as_float((int)(c2 >> 32)) : 0.f;
        float n3 = (p + 3 < p1) ? __int_as_float((int)(c3 >> 32)) : 0.f;
        const f16* r0 = XL + (size_t)s0 * 192;
        const f16* r1 = XL + (size_t)s1 * 192;
        const f16* r2 = XL + (size_t)s2 * 192;
        const f16* r3 = XL + (size_t)s3 * 192;
        f16x8 a0 = *(const f16x8*)(r0 + t * 8);
        f16x8 a1 = *(const f16x8*)(r1 + t * 8);
        f16x8 a2 = *(const f16x8*)(r2 + t * 8);
        f16x8 a3 = *(const f16x8*)(r3 + t * 8);
        f16x4 q0 = *(const f16x4*)(r0 + 128 + t * 4);
        f16x4 q1 = *(const f16x4*)(r1 + 128 + t * 4);
        f16x4 q2 = *(const f16x4*)(r2 + 128 + t * 4);
        f16x4 q3 = *(const f16x4*)(r3 + 128 + t * 4);
#pragma unroll
        for (int j = 0; j < 8; ++j)
            accA[j] += ((float)a0[j] * n0 + (float)a1[j] * n1) +
                       ((float)a2[j] * n2 + (float)a3[j] * n3);
#pragma unroll
        for (int j = 0; j < 4; ++j)
            accC[j] += ((float)q0[j] * n0 + (float)q1[j] * n1) +
                       ((float)q2[j] * n2 + (float)q3[j] * n3);
        p = pn;
    }

#pragma unroll
    for (int j = 0; j < 8; ++j) accA[j] = tanhf(accA[j]);

    union { f16 h[8]; u32x4 u; } oa;
#pragma unroll
    for (int j = 0; j < 8; ++j) oa.h[j] = (f16)accA[j];
    __builtin_nontemporal_store(oa.u, (u32x4*)(out + (size_t)node * 256 + t * 8));
    union { f16 h[4]; u32x2 u; } oc;
#pragma unroll
    for (int j = 0; j < 4; ++j) oc.h[j] = (f16)accC[j];
    __builtin_nontemporal_store(oc.u, (u32x2*)(out + (size_t)node * 256 + 128 + t * 4));
}

// ---------------------------------------------------------------------------
extern "C" void kernel_launch(void* const* d_in, const int* in_sizes, int n_in,
                              void* d_out, int out_size, void* d_ws, size_t ws_size,
                              hipStream_t stream) {
    const int FD = 256;

    const float* feature   = (const float*)d_in[0];
    const float* condition = (const float*)d_in[1];
    const int*   edge      = (const int*)d_in[2];
    const float* W_f2h = (const float*)d_in[3];
    const float* b_f2h = (const float*)d_in[4];
    const float* W_c2h = (const float*)d_in[5];
    const float* b_c2h = (const float*)d_in[6];
    const float* W_h2h = (const float*)d_in[7];
    const float* b_h2h = (const float*)d_in[8];
    const float* W_h2l = (const float*)d_in[9];
    const float* b_h2l = (const float*)d_in[10];
    float* out = (float*)d_out;

    const int N = in_sizes[0] / FD;   // 100000
    const int E = in_sizes[2] / 2;    // 1600000
    const int* src = edge;
    const int* dst = edge + E;

    // workspace layout
    float* ws_f   = (float*)d_ws;
    float* dinv   = ws_f;                                // N floats
    int*   count  = (int*)(ws_f + N);                    // N ints
    int*   rowp   = count + N;                           // N+1 ints
    int*   bsums  = rowp + N + 1;                        // 1024 ints
    int*   rank   = bsums + 1024;                        // E ints
    long long* csr = (long long*)(((uintptr_t)(rank + E) + 15) & ~(uintptr_t)15);  // E x 8B
    f16*   XL     = (f16*)(csr + E);                     // N*192 f16 ([xlA|cond]; reused compact later)
    f16*   B_h    = XL + (size_t)N * 192;                // N*256 f16 (h; strip reuse)
    f16*   wt1h   = B_h + (size_t)N * 256;               // 128*256
    f16*   wt1l   = wt1h + 128 * 256;
    f16*   wt2h   = wt1l + 128 * 256;                    // 128*64
    f16*   wt2l   = wt2h + 128 * 64;
    f16*   wt3h   = wt2l + 128 * 64;                     // 128*256
    f16*   wt3l   = wt3h + 128 * 256;
    f16*   wt4h   = wt3l + 128 * 256;                    // 64*128
    f16*   wt4l   = wt4h + 64 * 128;

    const int TB = 256;
    dim3 blk(TB);
    const int nScanBlocks = (N + SCAN_TILE - 1) / SCAN_TILE;  // 49

    // --- weight prep + condition convert into XL strip ---
    wprep_kernel<<<(256 * 128 + TB - 1) / TB, blk, 0, stream>>>(W_f2h, wt1h, wt1l, 256, 128);
    wprep_kernel<<<(64 * 128 + TB - 1) / TB, blk, 0, stream>>>(W_c2h, wt2h, wt2l, 64, 128);
    wprep_kernel<<<(256 * 128 + TB - 1) / TB, blk, 0, stream>>>(W_h2h, wt3h, wt3l, 256, 128);
    wprep_kernel<<<(128 * 64 + TB - 1) / TB, blk, 0, stream>>>(W_h2l, wt4h, wt4l, 128, 64);
    cond_to_xl_kernel<<<(N * 16 + TB - 1) / TB, blk, 0, stream>>>(condition, XL, N);

    // --- CSR build + norms (atomic-free fill via rank) ---
    count_zero_kernel<<<(N + TB - 1) / TB, blk, 0, stream>>>(count, N);
    count_rank_kernel<<<(E + TB - 1) / TB, blk, 0, stream>>>(dst, count, rank, E);
    dinv_kernel<<<(N + TB - 1) / TB, blk, 0, stream>>>(count, dinv, N);
    scan_partial_kernel<<<nScanBlocks, blk, 0, stream>>>(count, bsums, N);
    scan_blocksums_kernel<<<1, 1024, 0, stream>>>(bsums, nScanBlocks);
    scan_final_kernel<<<nScanBlocks, blk, 0, stream>>>(count, bsums, rowp, N);
    fill_kernel<<<(E + TB - 1) / TB, blk, 0, stream>>>(src, dst, rank, dinv, rowp, csr, E);

    const int gemm_grid = (N + 127) / 128;               // 782
    const int g128 = (N * 16 + TB - 1) / TB;             // gather grid, TPN=16
    const int g64  = (N * 8 + TB - 1) / TB;              // gather grid, TPN=8

    // --- conv1 GEMM: feature@W1 -> XL[:,0:128] (ld 192) ---
    gemm_mfma_kernel<256, 128, false, false><<<gemm_grid, blk, 0, stream>>>(
        feature, wt1h, wt1l, nullptr, XL, 192, 0, 256, N);

    // --- fused gather conv1+conv2: one CSR sweep ---
    //   B_h[:,0:128]  = tanh(P*(feature@W1) + b_f2h)
    //   B_h[:,128:192] = P*cond   (cprop, consumed in place by GEMM2)
    gather_fused_kernel<<<g128, blk, 0, stream>>>(
        XL, b_f2h, dinv, rowp, csr, B_h, N);

    // --- conv2 GEMM: tanh(cprop@W2 + b) -> B_h[:,128:256] (in-place strip read) ---
    gemm_mfma_kernel<64, 128, true, true><<<gemm_grid, blk, 0, stream>>>(
        (const void*)(B_h + 128), wt2h, wt2l, b_c2h, B_h, 256, 128, 256, N);

    // --- conv3: h2 = tanh(P (h @ W_h2h) + b) ---
    gemm_mfma_kernel<256, 128, false, true><<<gemm_grid, blk, 0, stream>>>(
        B_h, wt3h, wt3l, nullptr, XL, 128, 0, 256, N);
    gather_h_kernel<128, true, true, false><<<g128, blk, 0, stream>>>(
        XL, b_h2h, dinv, rowp, csr, B_h, 128, 0, N);

    // --- conv4: z = P (h2 @ W_h2l) + b -> fp32 out ---
    gemm_mfma_kernel<128, 64, false, true><<<gemm_grid, blk, 0, stream>>>(
        B_h, wt4h, wt4l, nullptr, XL, 64, 0, 128, N);
    gather_h_kernel<64, false, true, true><<<g64, blk, 0, stream>>>(
        XL, b_h2l, dinv, rowp, csr, out, 64, 0, N);
}